// Round 1
// baseline (1033.286 us; speedup 1.0000x reference)
//
#include <hip/hip_runtime.h>
#include <hip/hip_bf16.h>
#include <math.h>

#define T_TOKENS 2048
#define DMODEL   1024
#define HID      4096
#define NEXP     8

typedef float  f32x4  __attribute__((ext_vector_type(4)));
typedef short  bf16x8 __attribute__((ext_vector_type(8)));
typedef unsigned short u16x8 __attribute__((ext_vector_type(8)));

__device__ __forceinline__ unsigned short f2bf(float f) {
    union { float f; unsigned u; } v; v.f = f;
    unsigned u = v.u;
    unsigned r = (u + 0x7FFFu + ((u >> 16) & 1u)) >> 16;   // RNE
    return (unsigned short)r;
}

// ---------------- router: logits -> top2 -> sigmoid weight ----------------
__global__ void router_kernel(const float* __restrict__ x, const float* __restrict__ Wr,
                              int* counts, int* expert_of, int* slot_of, float* wt_of) {
    int t = blockIdx.x;
    int lane = threadIdx.x;
    const float* xr = x + (size_t)t * DMODEL;
    float p[NEXP];
#pragma unroll
    for (int e = 0; e < NEXP; ++e) p[e] = 0.f;
    for (int d = lane; d < DMODEL; d += 64) {
        float xv = xr[d];
        const float* wr = Wr + (size_t)d * NEXP;
#pragma unroll
        for (int e = 0; e < NEXP; ++e) p[e] += xv * wr[e];
    }
#pragma unroll
    for (int e = 0; e < NEXP; ++e) {
        for (int off = 32; off > 0; off >>= 1)
            p[e] += __shfl_down(p[e], off, 64);
    }
    if (lane == 0) {
        int i0 = 0; float v0 = p[0];
        for (int e = 1; e < NEXP; ++e) if (p[e] > v0) { v0 = p[e]; i0 = e; }
        float v1 = -INFINITY;
        for (int e = 0; e < NEXP; ++e) if (e != i0 && p[e] > v1) v1 = p[e];
        float w = 1.f / (1.f + expf(v1 - v0));   // softmax over top-2, top1 weight
        expert_of[t] = i0;
        wt_of[t] = w;
        slot_of[t] = atomicAdd(&counts[i0], 1);
    }
}

__global__ void scan_kernel(const int* counts, int* offsets) {
    if (threadIdx.x == 0 && blockIdx.x == 0) {
        int run = 0;
        for (int e = 0; e < NEXP; ++e) { offsets[e] = run; run += counts[e]; }
    }
}

__global__ void scatter_kernel(const int* offsets, const int* expert_of,
                               const int* slot_of, int* perm) {
    int t = blockIdx.x * blockDim.x + threadIdx.x;
    if (t < T_TOKENS) perm[offsets[expert_of[t]] + slot_of[t]] = t;
}

// ---------------- GEMM1: H[row] = GELU(X[perm[row]] @ W1[e])  (bf16 out) ----
// 128x128 tile, BK=64, 4 waves (2x2), 16x16x32 bf16 MFMA
__global__ __launch_bounds__(256, 2) void gemm1_kernel(
    const float* __restrict__ x, const float* __restrict__ W1,
    const int* __restrict__ counts, const int* __restrict__ offsets,
    const int* __restrict__ perm, unsigned short* __restrict__ H) {

    const int MT = T_TOKENS / 128;   // 16
    const int NT = HID / 128;        // 32
    int gid = blockIdx.x;
    int e   = gid / (MT * NT);
    int rem = gid % (MT * NT);
    int mt  = rem / NT;
    int nt  = rem % NT;
    int rows_e = counts[e];
    int m0 = mt * 128;
    if (m0 >= rows_e) return;
    int n0 = nt * 128;
    int base = offsets[e];

    __shared__ unsigned short Alds[128 * 64];   // [m][k] bf16
    __shared__ unsigned short Blds[128 * 64];   // [n][k] bf16 (transposed)
    __shared__ int rowTok[128];

    int tid  = threadIdx.x;
    int lane = tid & 63;
    int wid  = tid >> 6;
    int wm = wid >> 1, wn = wid & 1;

    if (tid < 128) {
        int r = m0 + tid;
        rowTok[tid] = (r < rows_e) ? perm[base + r] : -1;
    }

    f32x4 acc[4][4];
#pragma unroll
    for (int i = 0; i < 4; ++i)
#pragma unroll
        for (int j = 0; j < 4; ++j)
            acc[i][j] = (f32x4){0.f, 0.f, 0.f, 0.f};

    for (int k0 = 0; k0 < DMODEL; k0 += 64) {
        __syncthreads();
        // ---- stage A: X rows (gathered), fp32 -> bf16
        {
            int kg = tid & 15;        // k group of 4
            int rb = tid >> 4;        // 0..15
#pragma unroll
            for (int p = 0; p < 8; ++p) {
                int r = p * 16 + rb;
                int tok = rowTok[r];
                float4 v = make_float4(0.f, 0.f, 0.f, 0.f);
                if (tok >= 0)
                    v = *(const float4*)(x + (size_t)tok * DMODEL + k0 + kg * 4);
                ushort4 b;
                b.x = f2bf(v.x); b.y = f2bf(v.y); b.z = f2bf(v.z); b.w = f2bf(v.w);
                *(ushort4*)&Alds[r * 64 + kg * 4] = b;
            }
        }
        // ---- stage B transposed: W1[e][k][n] (n contiguous) -> Blds[n][k]
        {
            int nl   = tid & 127;
            int half = tid >> 7;      // 0..1 -> k halves of 32
            const float* bsrc = W1 + ((size_t)e * DMODEL + k0 + half * 32) * HID + n0 + nl;
#pragma unroll
            for (int kk = 0; kk < 32; kk += 4) {
                float f0 = bsrc[(size_t)(kk + 0) * HID];
                float f1 = bsrc[(size_t)(kk + 1) * HID];
                float f2 = bsrc[(size_t)(kk + 2) * HID];
                float f3 = bsrc[(size_t)(kk + 3) * HID];
                ushort4 b;
                b.x = f2bf(f0); b.y = f2bf(f1); b.z = f2bf(f2); b.w = f2bf(f3);
                *(ushort4*)&Blds[nl * 64 + half * 32 + kk] = b;
            }
        }
        __syncthreads();
#pragma unroll
        for (int ks = 0; ks < 2; ++ks) {
            int kq = ks * 32 + (lane >> 4) * 8;
            bf16x8 af[4], bfr[4];
#pragma unroll
            for (int i = 0; i < 4; ++i) {
                int m = wm * 64 + i * 16 + (lane & 15);
                af[i] = *(const bf16x8*)&Alds[m * 64 + kq];
                int n = wn * 64 + i * 16 + (lane & 15);
                bfr[i] = *(const bf16x8*)&Blds[n * 64 + kq];
            }
#pragma unroll
            for (int i = 0; i < 4; ++i)
#pragma unroll
                for (int j = 0; j < 4; ++j)
                    acc[i][j] = __builtin_amdgcn_mfma_f32_16x16x32_bf16(af[i], bfr[j], acc[i][j], 0, 0, 0);
        }
    }

    // ---- epilogue: exact GELU, store bf16 H at sorted row index
    int quad = lane >> 4, col = lane & 15;
#pragma unroll
    for (int i = 0; i < 4; ++i) {
#pragma unroll
        for (int j = 0; j < 4; ++j) {
#pragma unroll
            for (int r = 0; r < 4; ++r) {
                int ml = wm * 64 + i * 16 + quad * 4 + r;
                if (m0 + ml < rows_e) {
                    int n = n0 + wn * 64 + j * 16 + col;
                    float v = acc[i][j][r];
                    float g = 0.5f * v * (1.0f + erff(v * 0.70710678118654752f));
                    H[(size_t)(base + m0 + ml) * HID + n] = f2bf(g);
                }
            }
        }
    }
}

// ---------------- GEMM2: out[tok] = wt[tok] * (H[row] @ W2[e]) -------------
__global__ __launch_bounds__(256, 2) void gemm2_kernel(
    const unsigned short* __restrict__ H, const float* __restrict__ W2,
    const int* __restrict__ counts, const int* __restrict__ offsets,
    const int* __restrict__ perm, const float* __restrict__ wt_of,
    float* __restrict__ out) {

    const int MT = T_TOKENS / 128;   // 16
    const int NT = DMODEL / 128;     // 8
    int gid = blockIdx.x;
    int e   = gid / (MT * NT);
    int rem = gid % (MT * NT);
    int mt  = rem / NT;
    int nt  = rem % NT;
    int rows_e = counts[e];
    int m0 = mt * 128;
    if (m0 >= rows_e) return;
    int n0 = nt * 128;
    int base = offsets[e];

    __shared__ unsigned short Alds[128 * 64];   // [m][k]
    __shared__ unsigned short Blds[128 * 64];   // [n][k] transposed
    __shared__ int   rowTok[128];
    __shared__ float rowW[128];

    int tid  = threadIdx.x;
    int lane = tid & 63;
    int wid  = tid >> 6;
    int wm = wid >> 1, wn = wid & 1;

    if (tid < 128) {
        int r = m0 + tid;
        if (r < rows_e) {
            int tok = perm[base + r];
            rowTok[tid] = tok;
            rowW[tid]   = wt_of[tok];
        } else {
            rowTok[tid] = -1;
            rowW[tid]   = 0.f;
        }
    }

    f32x4 acc[4][4];
#pragma unroll
    for (int i = 0; i < 4; ++i)
#pragma unroll
        for (int j = 0; j < 4; ++j)
            acc[i][j] = (f32x4){0.f, 0.f, 0.f, 0.f};

    for (int k0 = 0; k0 < HID; k0 += 64) {
        __syncthreads();
        // ---- stage A: H rows (bf16, contiguous in sorted order)
        {
            int kg = tid & 7;         // k group of 8
            int rb = tid >> 3;        // 0..31
#pragma unroll
            for (int p = 0; p < 4; ++p) {
                int r = p * 32 + rb;
                u16x8 v = (u16x8)(unsigned short)0;
                if (m0 + r < rows_e)
                    v = *(const u16x8*)(H + (size_t)(base + m0 + r) * HID + k0 + kg * 8);
                *(u16x8*)&Alds[r * 64 + kg * 8] = v;
            }
        }
        // ---- stage B transposed: W2[e][k][n] -> Blds[n][k]
        {
            int nl   = tid & 127;
            int half = tid >> 7;
            const float* bsrc = W2 + ((size_t)e * HID + k0 + half * 32) * DMODEL + n0 + nl;
#pragma unroll
            for (int kk = 0; kk < 32; kk += 4) {
                float f0 = bsrc[(size_t)(kk + 0) * DMODEL];
                float f1 = bsrc[(size_t)(kk + 1) * DMODEL];
                float f2 = bsrc[(size_t)(kk + 2) * DMODEL];
                float f3 = bsrc[(size_t)(kk + 3) * DMODEL];
                ushort4 b;
                b.x = f2bf(f0); b.y = f2bf(f1); b.z = f2bf(f2); b.w = f2bf(f3);
                *(ushort4*)&Blds[nl * 64 + half * 32 + kk] = b;
            }
        }
        __syncthreads();
#pragma unroll
        for (int ks = 0; ks < 2; ++ks) {
            int kq = ks * 32 + (lane >> 4) * 8;
            bf16x8 af[4], bfr[4];
#pragma unroll
            for (int i = 0; i < 4; ++i) {
                int m = wm * 64 + i * 16 + (lane & 15);
                af[i] = *(const bf16x8*)&Alds[m * 64 + kq];
                int n = wn * 64 + i * 16 + (lane & 15);
                bfr[i] = *(const bf16x8*)&Blds[n * 64 + kq];
            }
#pragma unroll
            for (int i = 0; i < 4; ++i)
#pragma unroll
                for (int j = 0; j < 4; ++j)
                    acc[i][j] = __builtin_amdgcn_mfma_f32_16x16x32_bf16(af[i], bfr[j], acc[i][j], 0, 0, 0);
        }
    }

    // ---- epilogue: scale by gate weight, scatter to token row
    int quad = lane >> 4, col = lane & 15;
#pragma unroll
    for (int i = 0; i < 4; ++i) {
#pragma unroll
        for (int j = 0; j < 4; ++j) {
#pragma unroll
            for (int r = 0; r < 4; ++r) {
                int ml = wm * 64 + i * 16 + quad * 4 + r;
                if (m0 + ml < rows_e) {
                    int tok = rowTok[ml];
                    float w = rowW[ml];
                    int n = n0 + wn * 64 + j * 16 + col;
                    out[(size_t)tok * DMODEL + n] = w * acc[i][j][r];
                }
            }
        }
    }
}

extern "C" void kernel_launch(void* const* d_in, const int* in_sizes, int n_in,
                              void* d_out, int out_size, void* d_ws, size_t ws_size,
                              hipStream_t stream) {
    const float* x  = (const float*)d_in[0];
    const float* Wr = (const float*)d_in[1];
    const float* W1 = (const float*)d_in[2];
    const float* W2 = (const float*)d_in[3];
    float* out = (float*)d_out;

    char* ws = (char*)d_ws;
    int*   counts    = (int*)(ws);
    int*   offsets   = (int*)(ws + 32);
    int*   expert_of = (int*)(ws + 64);
    int*   slot_of   = (int*)(ws + 64 + 8192);
    float* wt_of     = (float*)(ws + 64 + 16384);
    int*   perm      = (int*)(ws + 64 + 24576);
    unsigned short* H = (unsigned short*)(ws + 65536);   // 2048 x 4096 bf16 = 16 MB

    hipMemsetAsync(counts, 0, 64, stream);
    router_kernel<<<T_TOKENS, 64, 0, stream>>>(x, Wr, counts, expert_of, slot_of, wt_of);
    scan_kernel<<<1, 64, 0, stream>>>(counts, offsets);
    scatter_kernel<<<T_TOKENS / 256, 256, 0, stream>>>(offsets, expert_of, slot_of, perm);
    gemm1_kernel<<<NEXP * (T_TOKENS / 128) * (HID / 128), 256, 0, stream>>>(
        x, W1, counts, offsets, perm, H);
    gemm2_kernel<<<NEXP * (T_TOKENS / 128) * (DMODEL / 128), 256, 0, stream>>>(
        H, W2, counts, offsets, perm, wt_of, out);
}

// Round 2
// 442.741 us; speedup vs baseline: 2.3338x; 2.3338x over previous
//
#include <hip/hip_runtime.h>
#include <hip/hip_bf16.h>
#include <math.h>

#define T_TOKENS 2048
#define DMODEL   1024
#define HID      4096
#define NEXP     8
#define MAX_TILES 32

typedef float  f32x4  __attribute__((ext_vector_type(4)));
typedef short  bf16x8 __attribute__((ext_vector_type(8)));
typedef unsigned short u16x8 __attribute__((ext_vector_type(8)));

__device__ __forceinline__ unsigned short f2bf(float f) {
    union { float f; unsigned u; } v; v.f = f;
    unsigned u = v.u;
    unsigned r = (u + 0x7FFFu + ((u >> 16) & 1u)) >> 16;   // RNE
    return (unsigned short)r;
}

__device__ __forceinline__ void async_copy16(const void* g, void* l) {
    __builtin_amdgcn_global_load_lds(
        (const __attribute__((address_space(1))) void*)g,
        (__attribute__((address_space(3))) void*)l,
        16, 0, 0);
}

// ---------------- router: logits -> top2 -> softmax-top1 weight ------------
__global__ void router_kernel(const float* __restrict__ x, const float* __restrict__ Wr,
                              int* counts, int* expert_of, int* slot_of, float* wt_of) {
    int t = blockIdx.x;
    int lane = threadIdx.x;
    const float* xr = x + (size_t)t * DMODEL;
    float p[NEXP];
#pragma unroll
    for (int e = 0; e < NEXP; ++e) p[e] = 0.f;
    for (int d = lane; d < DMODEL; d += 64) {
        float xv = xr[d];
        const float* wr = Wr + (size_t)d * NEXP;
#pragma unroll
        for (int e = 0; e < NEXP; ++e) p[e] += xv * wr[e];
    }
#pragma unroll
    for (int e = 0; e < NEXP; ++e) {
        for (int off = 32; off > 0; off >>= 1)
            p[e] += __shfl_down(p[e], off, 64);
    }
    if (lane == 0) {
        int i0 = 0; float v0 = p[0];
        for (int e = 1; e < NEXP; ++e) if (p[e] > v0) { v0 = p[e]; i0 = e; }
        float v1 = -INFINITY;
        for (int e = 0; e < NEXP; ++e) if (e != i0 && p[e] > v1) v1 = p[e];
        float w = 1.f / (1.f + expf(v1 - v0));
        expert_of[t] = i0;
        wt_of[t] = w;
        slot_of[t] = atomicAdd(&counts[i0], 1);
    }
}

// scan + tile-list build (<=24 tiles of M=128)
__global__ void scan_kernel(const int* counts, int* offsets,
                            int* tileE, int* tileM, int* tileCount) {
    if (threadIdx.x == 0 && blockIdx.x == 0) {
        int run = 0, tc = 0;
        for (int e = 0; e < NEXP; ++e) {
            offsets[e] = run;
            for (int m0 = 0; m0 < counts[e]; m0 += 128) {
                tileE[tc] = e; tileM[tc] = m0; ++tc;
            }
            run += counts[e];
        }
        *tileCount = tc;
    }
}

__global__ void scatter_kernel(const int* offsets, const int* expert_of,
                               const int* slot_of, int* perm) {
    int t = blockIdx.x * blockDim.x + threadIdx.x;
    if (t < T_TOKENS) perm[offsets[expert_of[t]] + slot_of[t]] = t;
}

// ---------------- fp32 [e][K][N] -> bf16 [e][N][K] ------------------------
__global__ __launch_bounds__(256) void convert_transpose_kernel(
    const float* __restrict__ W, unsigned short* __restrict__ WT, int K, int N) {
    int ktiles = K >> 6, ntiles = N >> 6;
    int gid = blockIdx.x;
    int e   = gid / (ktiles * ntiles);
    int r   = gid % (ktiles * ntiles);
    int kt  = r / ntiles, nt = r % ntiles;
    const float* src = W + (size_t)e * K * N + (size_t)(kt * 64) * N + nt * 64;
    unsigned short* dst = WT + (size_t)e * N * K + (size_t)(nt * 64) * K + kt * 64;

    __shared__ unsigned short tile[64][66];
    int tid = threadIdx.x;
    int n4 = (tid & 15) * 4;
    int kk = tid >> 4;
#pragma unroll
    for (int p = 0; p < 4; ++p) {
        int k = kk + p * 16;
        float4 v = *(const float4*)(src + (size_t)k * N + n4);
        tile[n4 + 0][k] = f2bf(v.x);
        tile[n4 + 1][k] = f2bf(v.y);
        tile[n4 + 2][k] = f2bf(v.z);
        tile[n4 + 3][k] = f2bf(v.w);
    }
    __syncthreads();
    int n = tid >> 2, ks = (tid & 3) * 16;
    unsigned short tmp[16];
#pragma unroll
    for (int i = 0; i < 16; ++i) tmp[i] = tile[n][ks + i];
    *(u16x8*)(dst + (size_t)n * K + ks)     = *(u16x8*)&tmp[0];
    *(u16x8*)(dst + (size_t)n * K + ks + 8) = *(u16x8*)&tmp[8];
}

// ---------------- x fp32 -> bf16 streaming --------------------------------
__global__ __launch_bounds__(256) void convert_x_kernel(
    const float* __restrict__ x, unsigned short* __restrict__ xbf) {
    int i = (blockIdx.x * 256 + threadIdx.x) * 4;
    float4 v = *(const float4*)(x + i);
    ushort4 b;
    b.x = f2bf(v.x); b.y = f2bf(v.y); b.z = f2bf(v.z); b.w = f2bf(v.w);
    *(ushort4*)(xbf + i) = b;
}

// ---------------- GEMM1: H = GELU(Xbf[perm] @ W1T^T), bf16 out -------------
__global__ __launch_bounds__(256, 2) void gemm1_kernel(
    const unsigned short* __restrict__ Xbf, const unsigned short* __restrict__ W1T,
    const int* __restrict__ counts, const int* __restrict__ offsets,
    const int* __restrict__ perm, const int* __restrict__ tileE,
    const int* __restrict__ tileM, const int* __restrict__ tileCount,
    unsigned short* __restrict__ H) {

    const int NT = HID / 128;                 // 32
    int tile = blockIdx.x / NT;
    int nt   = blockIdx.x % NT;
    if (tile >= *tileCount) return;
    int e = tileE[tile], m0 = tileM[tile];
    int rows_e = counts[e], base = offsets[e];
    int n0 = nt * 128;

    __shared__ unsigned short Alds[128 * 64];
    __shared__ unsigned short Blds[128 * 64];

    int tid  = threadIdx.x;
    int lane = tid & 63;
    int wid  = tid >> 6;
    int wm = wid >> 1, wn = wid & 1;

    // precompute staging addresses: idx = p*256+tid; row = idx>>3, seg = idx&7
    const unsigned short* ag[4]; const unsigned short* bg[4];
    unsigned short* al[4]; unsigned short* bl[4];
#pragma unroll
    for (int p = 0; p < 4; ++p) {
        int idx = p * 256 + tid;
        int row = idx >> 3, seg = idx & 7;
        int r = m0 + row;
        int tok = perm[base + (r < rows_e ? r : rows_e - 1)];
        ag[p] = Xbf + (size_t)tok * DMODEL + seg * 8;
        bg[p] = W1T + ((size_t)e * HID + n0 + row) * DMODEL + seg * 8;
        al[p] = &Alds[idx * 8];
        bl[p] = &Blds[idx * 8];
    }

    f32x4 acc[4][4];
#pragma unroll
    for (int i = 0; i < 4; ++i)
#pragma unroll
        for (int j = 0; j < 4; ++j) acc[i][j] = (f32x4){0.f, 0.f, 0.f, 0.f};

    for (int k0 = 0; k0 < DMODEL; k0 += 64) {
        __syncthreads();
#pragma unroll
        for (int p = 0; p < 4; ++p) {
            async_copy16(ag[p] + k0, al[p]);
            async_copy16(bg[p] + k0, bl[p]);
        }
        __syncthreads();
#pragma unroll
        for (int ks = 0; ks < 2; ++ks) {
            int kq = ks * 32 + (lane >> 4) * 8;
            bf16x8 af[4], bfr[4];
#pragma unroll
            for (int i = 0; i < 4; ++i) {
                int m = wm * 64 + i * 16 + (lane & 15);
                af[i] = *(const bf16x8*)&Alds[m * 64 + kq];
                int n = wn * 64 + i * 16 + (lane & 15);
                bfr[i] = *(const bf16x8*)&Blds[n * 64 + kq];
            }
#pragma unroll
            for (int i = 0; i < 4; ++i)
#pragma unroll
                for (int j = 0; j < 4; ++j)
                    acc[i][j] = __builtin_amdgcn_mfma_f32_16x16x32_bf16(af[i], bfr[j], acc[i][j], 0, 0, 0);
        }
    }

    int quad = lane >> 4, col = lane & 15;
#pragma unroll
    for (int i = 0; i < 4; ++i)
#pragma unroll
        for (int j = 0; j < 4; ++j)
#pragma unroll
            for (int r = 0; r < 4; ++r) {
                int ml = wm * 64 + i * 16 + quad * 4 + r;
                if (m0 + ml < rows_e) {
                    int n = n0 + wn * 64 + j * 16 + col;
                    float v = acc[i][j][r];
                    float g = 0.5f * v * (1.0f + erff(v * 0.70710678118654752f));
                    H[(size_t)(base + m0 + ml) * HID + n] = f2bf(g);
                }
            }
}

// ---------------- GEMM2 (split-K=4): out += wt * (H @ W2T^T) ---------------
__global__ __launch_bounds__(256, 2) void gemm2_kernel(
    const unsigned short* __restrict__ H, const unsigned short* __restrict__ W2T,
    const int* __restrict__ counts, const int* __restrict__ offsets,
    const int* __restrict__ perm, const float* __restrict__ wt_of,
    const int* __restrict__ tileE, const int* __restrict__ tileM,
    const int* __restrict__ tileCount, float* __restrict__ out) {

    const int NT = DMODEL / 128;              // 8
    const int SK = 4;                         // split-K
    int tile = blockIdx.x / (NT * SK);
    int rem  = blockIdx.x % (NT * SK);
    int nt   = rem / SK;
    int sk   = rem % SK;
    if (tile >= *tileCount) return;
    int e = tileE[tile], m0 = tileM[tile];
    int rows_e = counts[e], base = offsets[e];
    int n0 = nt * 128;
    int kbeg = sk * (HID / SK), kend = kbeg + (HID / SK);

    __shared__ unsigned short Alds[128 * 64];
    __shared__ unsigned short Blds[128 * 64];
    __shared__ int   rowTok[128];
    __shared__ float rowW[128];

    int tid  = threadIdx.x;
    int lane = tid & 63;
    int wid  = tid >> 6;
    int wm = wid >> 1, wn = wid & 1;

    if (tid < 128) {
        int r = m0 + tid;
        if (r < rows_e) {
            int tok = perm[base + r];
            rowTok[tid] = tok;
            rowW[tid]   = wt_of[tok];
        } else { rowTok[tid] = 0; rowW[tid] = 0.f; }
    }

    const unsigned short* ag[4]; const unsigned short* bg[4];
    unsigned short* al[4]; unsigned short* bl[4];
#pragma unroll
    for (int p = 0; p < 4; ++p) {
        int idx = p * 256 + tid;
        int row = idx >> 3, seg = idx & 7;
        int hr = base + m0 + row;
        if (hr > T_TOKENS - 1) hr = T_TOKENS - 1;
        ag[p] = H + (size_t)hr * HID + seg * 8;
        bg[p] = W2T + ((size_t)e * DMODEL + n0 + row) * HID + seg * 8;
        al[p] = &Alds[idx * 8];
        bl[p] = &Blds[idx * 8];
    }

    f32x4 acc[4][4];
#pragma unroll
    for (int i = 0; i < 4; ++i)
#pragma unroll
        for (int j = 0; j < 4; ++j) acc[i][j] = (f32x4){0.f, 0.f, 0.f, 0.f};

    for (int k0 = kbeg; k0 < kend; k0 += 64) {
        __syncthreads();
#pragma unroll
        for (int p = 0; p < 4; ++p) {
            async_copy16(ag[p] + k0, al[p]);
            async_copy16(bg[p] + k0, bl[p]);
        }
        __syncthreads();
#pragma unroll
        for (int ks = 0; ks < 2; ++ks) {
            int kq = ks * 32 + (lane >> 4) * 8;
            bf16x8 af[4], bfr[4];
#pragma unroll
            for (int i = 0; i < 4; ++i) {
                int m = wm * 64 + i * 16 + (lane & 15);
                af[i] = *(const bf16x8*)&Alds[m * 64 + kq];
                int n = wn * 64 + i * 16 + (lane & 15);
                bfr[i] = *(const bf16x8*)&Blds[n * 64 + kq];
            }
#pragma unroll
            for (int i = 0; i < 4; ++i)
#pragma unroll
                for (int j = 0; j < 4; ++j)
                    acc[i][j] = __builtin_amdgcn_mfma_f32_16x16x32_bf16(af[i], bfr[j], acc[i][j], 0, 0, 0);
        }
    }

    int quad = lane >> 4, col = lane & 15;
#pragma unroll
    for (int i = 0; i < 4; ++i)
#pragma unroll
        for (int j = 0; j < 4; ++j)
#pragma unroll
            for (int r = 0; r < 4; ++r) {
                int ml = wm * 64 + i * 16 + quad * 4 + r;
                if (m0 + ml < rows_e) {
                    int tok = rowTok[ml];
                    float w = rowW[ml];
                    int n = n0 + wn * 64 + j * 16 + col;
                    atomicAdd(&out[(size_t)tok * DMODEL + n], w * acc[i][j][r]);
                }
            }
}

extern "C" void kernel_launch(void* const* d_in, const int* in_sizes, int n_in,
                              void* d_out, int out_size, void* d_ws, size_t ws_size,
                              hipStream_t stream) {
    const float* x  = (const float*)d_in[0];
    const float* Wr = (const float*)d_in[1];
    const float* W1 = (const float*)d_in[2];
    const float* W2 = (const float*)d_in[3];
    float* out = (float*)d_out;

    char* ws = (char*)d_ws;
    int*   counts    = (int*)(ws);
    int*   offsets   = (int*)(ws + 64);
    int*   tileCount = (int*)(ws + 128);
    int*   tileE     = (int*)(ws + 256);
    int*   tileM     = (int*)(ws + 256 + 4 * MAX_TILES);
    int*   expert_of = (int*)(ws + 1024);
    int*   slot_of   = (int*)(ws + 1024 + 8192);
    float* wt_of     = (float*)(ws + 1024 + 16384);
    int*   perm      = (int*)(ws + 1024 + 24576);
    size_t off = 65536;
    unsigned short* Xbf = (unsigned short*)(ws + off);               off += (size_t)T_TOKENS * DMODEL * 2;  // 4 MB
    unsigned short* Hbuf = (unsigned short*)(ws + off);              off += (size_t)T_TOKENS * HID * 2;     // 16 MB
    unsigned short* W1T = (unsigned short*)(ws + off);               off += (size_t)NEXP * DMODEL * HID * 2; // 64 MB
    unsigned short* W2T = (unsigned short*)(ws + off);               // 64 MB

    hipMemsetAsync(counts, 0, 64, stream);
    hipMemsetAsync(out, 0, (size_t)T_TOKENS * DMODEL * sizeof(float), stream);

    router_kernel<<<T_TOKENS, 64, 0, stream>>>(x, Wr, counts, expert_of, slot_of, wt_of);
    scan_kernel<<<1, 64, 0, stream>>>(counts, offsets, tileE, tileM, tileCount);
    scatter_kernel<<<T_TOKENS / 256, 256, 0, stream>>>(offsets, expert_of, slot_of, perm);

    convert_x_kernel<<<(T_TOKENS * DMODEL) / 1024, 256, 0, stream>>>(x, Xbf);
    convert_transpose_kernel<<<NEXP * (DMODEL / 64) * (HID / 64), 256, 0, stream>>>(W1, W1T, DMODEL, HID);
    convert_transpose_kernel<<<NEXP * (HID / 64) * (DMODEL / 64), 256, 0, stream>>>(W2, W2T, HID, DMODEL);

    gemm1_kernel<<<MAX_TILES * (HID / 128), 256, 0, stream>>>(
        Xbf, W1T, counts, offsets, perm, tileE, tileM, tileCount, Hbuf);
    gemm2_kernel<<<MAX_TILES * (DMODEL / 128) * 4, 256, 0, stream>>>(
        Hbuf, W2T, counts, offsets, perm, wt_of, tileE, tileM, tileCount, out);
}